// Round 2
// baseline (609.856 us; speedup 1.0000x reference)
//
#include <hip/hip_runtime.h>

// ---------------------------------------------------------------------------
// MoE top-2 of 8 experts, SwiGLU. B=2,S=2048 -> T=4096 tokens, H=1024, I=2816.
// fp64 gating (selection fidelity), bf16 MFMA grouped GEMMs on top-2 rows.
// R5: fat wave tiles. gemm1/gemm2 were LDS-read-BW capped (640 B/MFMA ->
// ~48% MfmaUtil ceiling; measured 35%). Wave tile now 64 M-rows with 4x4
// fragment repeat (gemm1 dual g/u acc, gemm2 8x4): 384 B/MFMA -> ~82% cap.
// M-tile 256, BK=64, same 2-barrier structure + XOR swizzle (no new sync).
// k_prefix removed: gemm/build/combine derive offsets from cnt[8] per block.
// ---------------------------------------------------------------------------

namespace {
constexpr int TOKS = 4096;
constexpr int HDIM = 1024;
constexpr int IDIM = 2816;
constexpr int NEXP = 8;
constexpr int NROW = 8192;  // TOKS * 2 assignments
constexpr int MTILES = 40;  // >= worst-case sum of ceil(cnt_e/256)

// workspace layout (bytes)
constexpr size_t WGT_OFF = 0;                         // bf16 Wg^T  [E][I][H]
constexpr size_t WUT_OFF = 46137344;                  // bf16 Wu^T  [E][I][H]
constexpr size_t WDT_OFF = 92274688;                  // bf16 Wd^T  [E][H][I]
constexpr size_t A_OFF   = 138412032;                 // bf16 A     [8192][H]
constexpr size_t ACT_OFF = 155189248;                 // bf16 act   [8192][I]
constexpr size_t CNT_OFF = 201326592;                 // int[8]
constexpr size_t TIX_OFF = CNT_OFF + 1024;            // int4[4096] (e0,e1,r0,r1)
constexpr size_t TPR_OFF = CNT_OFF + 66560;           // float2[4096]
// partial fp32 [8192][H] aliases Wg^T region (GEMM1 done before GEMM2 writes)
constexpr size_t PRT_OFF = 0;                         // 33554432 <= 46137344
}  // namespace

typedef __attribute__((ext_vector_type(8))) short short8;
typedef __attribute__((ext_vector_type(8))) unsigned short ushort8;
typedef __attribute__((ext_vector_type(4))) float f32x4;

__device__ __forceinline__ unsigned short f2bf(float f) {
  union { float f; unsigned int u; } v; v.f = f;
  unsigned int u = v.u;
  return (unsigned short)((u + 0x7fffu + ((u >> 16) & 1u)) >> 16);  // RNE
}

__device__ __forceinline__ void gl2lds16(const void* g, void* l) {
  __builtin_amdgcn_global_load_lds(
      (const __attribute__((address_space(1))) void*)g,
      (__attribute__((address_space(3))) void*)l, 16, 0, 0);
}

// Derive (e, m0, off, ne) for 256-row m-tile index y from cnt[8]. e<0: no tile.
__device__ __forceinline__ void tile_map(const int* __restrict__ cnt, int y,
                                         int& e, int& m0, int& off, int& ne) {
  e = -1; m0 = 0; off = 0; ne = 0;
  int s = 0;
#pragma unroll
  for (int ee = 0; ee < NEXP; ++ee) {
    int c = cnt[ee];
    int nt = (c + 255) >> 8;
    if (e < 0) {
      if (y < nt) { e = ee; m0 = y << 8; off = s; ne = c; }
      else y -= nt;
    }
    s += c;
  }
}

// ------------- fused fp32 [R][C] -> bf16 [C][R] transpose (all 3 W) --------
// z: 0..7 = Wg expert e, 8..15 = Wu, 16..23 = Wd. 64x64 tiles, float4 reads,
// ushort8 stores. Block (0,0,0) also zeroes cnt[] (replaces k_init).
__global__ __launch_bounds__(256) void k_transpose_all(
    const float* __restrict__ Wg, const float* __restrict__ Wu,
    const float* __restrict__ Wd, unsigned short* __restrict__ WgT,
    unsigned short* __restrict__ WuT, unsigned short* __restrict__ WdT,
    int* __restrict__ cnt) {
  const int z = blockIdx.z;
  if (z == 0 && blockIdx.x == 0 && threadIdx.x < NEXP) cnt[threadIdx.x] = 0;
  const float* in; unsigned short* out; int C, R;
  if (z < 8)       { in = Wg; out = WgT; C = IDIM; R = HDIM; }
  else if (z < 16) { in = Wu; out = WuT; C = IDIM; R = HDIM; }
  else             { in = Wd; out = WdT; C = HDIM; R = IDIM; }
  const size_t eoff = (size_t)(z & 7) * HDIM * IDIM;
  in += eoff; out += eoff;
  const int nbx = C / 64;
  const int c0 = (blockIdx.x % nbx) * 64, r0 = (blockIdx.x / nbx) * 64;
  __shared__ float tile[64][65];
  const int tid = threadIdx.x;
  const int rr = tid >> 4, cc4 = (tid & 15) * 4;
#pragma unroll
  for (int i = 0; i < 4; ++i) {
    int r = rr + i * 16;
    float4 v = *(const float4*)(in + (size_t)(r0 + r) * C + c0 + cc4);
    tile[r][cc4 + 0] = v.x; tile[r][cc4 + 1] = v.y;
    tile[r][cc4 + 2] = v.z; tile[r][cc4 + 3] = v.w;
  }
  __syncthreads();
  const int j = tid & 7;  // 16B chunk within out row
#pragma unroll
  for (int i = 0; i < 2; ++i) {
    int c = (tid >> 3) + i * 32;
    ushort8 o;
#pragma unroll
    for (int k = 0; k < 8; ++k) o[k] = f2bf(tile[j * 8 + k][c]);
    *(ushort8*)(out + (size_t)(c0 + c) * R + r0 + j * 8) = o;
  }
}

// ------------------------------- gating ------------------------------------
__global__ __launch_bounds__(256) void k_gating(
    const float* __restrict__ x, const float* __restrict__ gw,
    float* __restrict__ logits_out, int* __restrict__ cnt,
    int4* __restrict__ tidx, float2* __restrict__ tprb) {
  const int lane = threadIdx.x & 63;
  const int t = blockIdx.x * 4 + (threadIdx.x >> 6);
  const float4* xr = (const float4*)(x + (size_t)t * HDIM);
  double acc[8];
#pragma unroll
  for (int e = 0; e < 8; ++e) acc[e] = 0.0;
#pragma unroll
  for (int jj = 0; jj < 4; ++jj) {
    float4 xv = xr[lane + jj * 64];
    const int hb = (lane + jj * 64) * 4;
    const float xs[4] = {xv.x, xv.y, xv.z, xv.w};
#pragma unroll
    for (int c = 0; c < 4; ++c) {
      const float4* g = (const float4*)(gw + (size_t)(hb + c) * 8);
      float4 g0 = g[0], g1 = g[1];
      acc[0] += (double)xs[c] * g0.x; acc[1] += (double)xs[c] * g0.y;
      acc[2] += (double)xs[c] * g0.z; acc[3] += (double)xs[c] * g0.w;
      acc[4] += (double)xs[c] * g1.x; acc[5] += (double)xs[c] * g1.y;
      acc[6] += (double)xs[c] * g1.z; acc[7] += (double)xs[c] * g1.w;
    }
  }
#pragma unroll
  for (int off = 32; off > 0; off >>= 1) {
#pragma unroll
    for (int e = 0; e < 8; ++e) acc[e] += __shfl_down(acc[e], off);
  }
  if (lane == 0) {
    float lg[8];
#pragma unroll
    for (int e = 0; e < 8; ++e) lg[e] = (float)acc[e];
#pragma unroll
    for (int e = 0; e < 8; ++e) logits_out[(size_t)t * 8 + e] = lg[e];
    float v0 = lg[0]; int i0 = 0; float v1 = -3.0e38f; int i1 = 0;
#pragma unroll
    for (int e = 1; e < 8; ++e) {
      if (lg[e] > v0) { v1 = v0; i1 = i0; v0 = lg[e]; i0 = e; }
      else if (lg[e] > v1) { v1 = lg[e]; i1 = e; }
    }
    float ex = expf(v1 - v0);
    float p0 = 1.0f / (1.0f + ex);
    float p1 = ex / (1.0f + ex);
    int r0 = atomicAdd(&cnt[i0], 1);   // within-expert rank
    int r1 = atomicAdd(&cnt[i1], 1);
    tidx[t] = make_int4(i0, i1, r0, r1);
    tprb[t] = make_float2(p0, p1);
  }
}

// --------------- gather x rows to compact bf16 A (no atomics) --------------
__global__ __launch_bounds__(256) void k_build(
    const float* __restrict__ x, const int4* __restrict__ tidx,
    const int* __restrict__ cnt, unsigned short* __restrict__ A) {
  const int t = blockIdx.x;
  const int4 ii = tidx[t];
  int o0 = 0, o1 = 0;
#pragma unroll
  for (int e = 0; e < NEXP - 1; ++e) {
    int c = cnt[e];
    o0 += (e < ii.x) ? c : 0;
    o1 += (e < ii.y) ? c : 0;
  }
  const int r0 = o0 + ii.z, r1 = o1 + ii.w;
  float4 v = ((const float4*)(x + (size_t)t * HDIM))[threadIdx.x];
  ushort4 b;
  b.x = f2bf(v.x); b.y = f2bf(v.y); b.z = f2bf(v.z); b.w = f2bf(v.w);
  ((ushort4*)(A + (size_t)r0 * HDIM))[threadIdx.x] = b;
  ((ushort4*)(A + (size_t)r1 * HDIM))[threadIdx.x] = b;
}

// ---------------- GEMM1: act = silu(A*Wg^T) * (A*Wu^T)  (bf16) -------------
// 256(M) x 64(N) tile, dual B, BK=64, 16x16x32 MFMA, XOR-swizzled LDS.
// 4 waves, each owns 64 M-rows with BOTH g and u 4x4 accumulators:
// per kk = af[4]+bg[4]+bu[4] = 12KB LDS read for 32 MFMA (384 B/MFMA).
__global__ __launch_bounds__(256, 2) void k_gemm1(
    const unsigned short* __restrict__ A, const unsigned short* __restrict__ WgT,
    const unsigned short* __restrict__ WuT, unsigned short* __restrict__ act,
    const int* __restrict__ cnt) {
  int e, m0, off, ne;
  tile_map(cnt, blockIdx.y, e, m0, off, ne);
  if (e < 0) return;
  const int n0 = blockIdx.x * 64;
  const unsigned short* Bg = WgT + ((size_t)e * IDIM + n0) * HDIM;
  const unsigned short* Bu = WuT + ((size_t)e * IDIM + n0) * HDIM;

  __shared__ unsigned short As[256 * 64];   // 32 KB
  __shared__ unsigned short Bgs[64 * 64];   // 8 KB
  __shared__ unsigned short Bus[64 * 64];   // 8 KB

  const int tid = threadIdx.x, w = tid >> 6, lane = tid & 63;
  const int lrow8 = lane >> 3;                       // 0..7 row in 1KB chunk
  const int swz = ((lane & 7) ^ lrow8) * 8;          // swizzled src column
  const int m16 = lane & 15, quad = lane >> 4, l7 = lane & 7;

  f32x4 accg[4][4], accu[4][4];
#pragma unroll
  for (int mi = 0; mi < 4; ++mi)
#pragma unroll
    for (int ni = 0; ni < 4; ++ni) {
      accg[mi][ni] = (f32x4){0.f, 0.f, 0.f, 0.f};
      accu[mi][ni] = (f32x4){0.f, 0.f, 0.f, 0.f};
    }

  for (int kt = 0; kt < HDIM / 64; ++kt) {
    const int k0 = kt * 64;
#pragma unroll
    for (int i = 0; i < 8; ++i) {
      int gr = off + m0 + w * 64 + i * 8 + lrow8;
      gr = gr > (NROW - 1) ? (NROW - 1) : gr;
      gl2lds16(A + (size_t)gr * HDIM + k0 + swz, &As[(w * 64 + i * 8) * 64]);
    }
#pragma unroll
    for (int i = 0; i < 2; ++i) {
      int rl = w * 16 + i * 8 + lrow8;
      gl2lds16(Bg + (size_t)rl * HDIM + k0 + swz, &Bgs[(w * 16 + i * 8) * 64]);
      gl2lds16(Bu + (size_t)rl * HDIM + k0 + swz, &Bus[(w * 16 + i * 8) * 64]);
    }
    __syncthreads();
#pragma unroll
    for (int kk = 0; kk < 2; ++kk) {
      const int jc = ((kk * 4 + quad) ^ l7) * 8;     // swizzled read column
      short8 af[4], bgf[4], buf[4];
#pragma unroll
      for (int mi = 0; mi < 4; ++mi)
        af[mi] = *(const short8*)&As[(w * 64 + mi * 16 + m16) * 64 + jc];
#pragma unroll
      for (int ni = 0; ni < 4; ++ni) {
        bgf[ni] = *(const short8*)&Bgs[(ni * 16 + m16) * 64 + jc];
        buf[ni] = *(const short8*)&Bus[(ni * 16 + m16) * 64 + jc];
      }
#pragma unroll
      for (int mi = 0; mi < 4; ++mi)
#pragma unroll
        for (int ni = 0; ni < 4; ++ni) {
          accg[mi][ni] = __builtin_amdgcn_mfma_f32_16x16x32_bf16(
              af[mi], bgf[ni], accg[mi][ni], 0, 0, 0);
          accu[mi][ni] = __builtin_amdgcn_mfma_f32_16x16x32_bf16(
              af[mi], buf[ni], accu[mi][ni], 0, 0, 0);
        }
    }
    __syncthreads();
  }
  // epilogue: silu(g)*u -> bf16, staged through As for 16B stores
#pragma unroll
  for (int mi = 0; mi < 4; ++mi)
#pragma unroll
    for (int ni = 0; ni < 4; ++ni)
#pragma unroll
      for (int r = 0; r < 4; ++r) {
        int ml = w * 64 + mi * 16 + quad * 4 + r;
        float g = accg[mi][ni][r];
        float u = accu[mi][ni][r];
        float s = g / (1.0f + __expf(-g));
        As[ml * 64 + ni * 16 + m16] = f2bf(s * u);
      }
  __syncthreads();
#pragma unroll
  for (int i = 0; i < 8; ++i) {
    int chunk = i * 256 + tid;
    int row = chunk >> 3, j = chunk & 7;
    if (m0 + row < ne)
      *(ushort8*)&act[(size_t)(off + m0 + row) * IDIM + n0 + j * 8] =
          *(const ushort8*)&As[row * 64 + j * 8];
  }
}

// ---------------- GEMM2: partial = act * Wd^T  (bf16 -> fp32) --------------
// 256x128 tile, 4 waves (2m x 2n), wave tile 128x64 (8x4 frags), BK=64.
__global__ __launch_bounds__(256, 2) void k_gemm2(
    const unsigned short* __restrict__ act, const unsigned short* __restrict__ WdT,
    float* __restrict__ partial, const int* __restrict__ cnt) {
  int e, m0, off, ne;
  tile_map(cnt, blockIdx.y, e, m0, off, ne);
  if (e < 0) return;
  const int n0 = blockIdx.x * 128;
  const unsigned short* B = WdT + ((size_t)e * HDIM + n0) * IDIM;

  __shared__ unsigned short As[256 * 64];   // 32 KB
  __shared__ unsigned short Bs[128 * 64];   // 16 KB

  const int tid = threadIdx.x, w = tid >> 6, lane = tid & 63;
  const int lrow8 = lane >> 3;
  const int swz = ((lane & 7) ^ lrow8) * 8;
  const int m16 = lane & 15, quad = lane >> 4, l7 = lane & 7;
  const int wm = (w >> 1) * 128, wn = (w & 1) * 64;

  f32x4 acc[8][4];
#pragma unroll
  for (int mi = 0; mi < 8; ++mi)
#pragma unroll
    for (int ni = 0; ni < 4; ++ni) acc[mi][ni] = (f32x4){0.f, 0.f, 0.f, 0.f};

  for (int kt = 0; kt < IDIM / 64; ++kt) {
    const int k0 = kt * 64;
#pragma unroll
    for (int i = 0; i < 8; ++i) {
      int gr = off + m0 + w * 64 + i * 8 + lrow8;
      gr = gr > (NROW - 1) ? (NROW - 1) : gr;
      gl2lds16(act + (size_t)gr * IDIM + k0 + swz, &As[(w * 64 + i * 8) * 64]);
    }
#pragma unroll
    for (int i = 0; i < 2; ++i) {
      int rl = w * 32 + i * 8 + lrow8;
      gl2lds16(B + (size_t)rl * IDIM + k0 + swz, &Bs[(w * 32 + i * 8) * 64]);
    }
    // waves 0/1 stage Bs rows 0..63, waves 2/3 stage rows 64..127 via i=2,3
#pragma unroll
    for (int i = 2; i < 4; ++i) {
      int rl = w * 32 + (i - 2) * 8 + lrow8 + 16;
      gl2lds16(B + (size_t)rl * IDIM + k0 + swz, &Bs[(w * 32 + 16 + (i - 2) * 8) * 64]);
    }
    __syncthreads();
#pragma unroll
    for (int kk = 0; kk < 2; ++kk) {
      const int jc = ((kk * 4 + quad) ^ l7) * 8;
      short8 af[8], bf[4];
#pragma unroll
      for (int mi = 0; mi < 8; ++mi)
        af[mi] = *(const short8*)&As[(wm + mi * 16 + m16) * 64 + jc];
#pragma unroll
      for (int ni = 0; ni < 4; ++ni)
        bf[ni] = *(const short8*)&Bs[(wn + ni * 16 + m16) * 64 + jc];
#pragma unroll
      for (int mi = 0; mi < 8; ++mi)
#pragma unroll
        for (int ni = 0; ni < 4; ++ni)
          acc[mi][ni] = __builtin_amdgcn_mfma_f32_16x16x32_bf16(
              af[mi], bf[ni], acc[mi][ni], 0, 0, 0);
    }
    __syncthreads();
  }
#pragma unroll
  for (int mi = 0; mi < 8; ++mi)
#pragma unroll
    for (int ni = 0; ni < 4; ++ni)
#pragma unroll
      for (int r = 0; r < 4; ++r) {
        int ml = wm + mi * 16 + quad * 4 + r;
        if (m0 + ml < ne)
          partial[(size_t)(off + m0 + ml) * HDIM + n0 + wn + ni * 16 + m16] =
              acc[mi][ni][r];
      }
}

// ------------------- combine: out = p0*row0 + p1*row1 ----------------------
__global__ __launch_bounds__(256) void k_combine(
    const float* __restrict__ partial, const int4* __restrict__ tidx,
    const int* __restrict__ cnt, const float2* __restrict__ tprb,
    float* __restrict__ out) {
  const int t = blockIdx.x;
  const int4 ii = tidx[t];
  int o0 = 0, o1 = 0;
#pragma unroll
  for (int e = 0; e < NEXP - 1; ++e) {
    int c = cnt[e];
    o0 += (e < ii.x) ? c : 0;
    o1 += (e < ii.y) ? c : 0;
  }
  const int r0 = o0 + ii.z, r1 = o1 + ii.w;
  const float2 p = tprb[t];
  float4 a = ((const float4*)(partial + (size_t)r0 * HDIM))[threadIdx.x];
  float4 b = ((const float4*)(partial + (size_t)r1 * HDIM))[threadIdx.x];
  float4 o;
  o.x = p.x * a.x + p.y * b.x;
  o.y = p.x * a.y + p.y * b.y;
  o.z = p.x * a.z + p.y * b.z;
  o.w = p.x * a.w + p.y * b.w;
  ((float4*)(out + (size_t)t * HDIM))[threadIdx.x] = o;
}

// ---------------------------------------------------------------------------
extern "C" void kernel_launch(void* const* d_in, const int* in_sizes, int n_in,
                              void* d_out, int out_size, void* d_ws, size_t ws_size,
                              hipStream_t stream) {
  const float* x  = (const float*)d_in[0];
  const float* gw = (const float*)d_in[1];
  const float* Wg = (const float*)d_in[2];
  const float* Wu = (const float*)d_in[3];
  const float* Wd = (const float*)d_in[4];
  float* out = (float*)d_out;
  char* ws = (char*)d_ws;

  unsigned short* WgT = (unsigned short*)(ws + WGT_OFF);
  unsigned short* WuT = (unsigned short*)(ws + WUT_OFF);
  unsigned short* WdT = (unsigned short*)(ws + WDT_OFF);
  unsigned short* A   = (unsigned short*)(ws + A_OFF);
  unsigned short* act = (unsigned short*)(ws + ACT_OFF);
  float* partial = (float*)(ws + PRT_OFF);
  int* cnt  = (int*)(ws + CNT_OFF);
  int4* tidx = (int4*)(ws + TIX_OFF);
  float2* tprb = (float2*)(ws + TPR_OFF);

  float* logits_out = out + (size_t)TOKS * HDIM;  // output 1 region

  // Wg,Wu: [H][I] -> [I][H]; Wd: [I][H] -> [H][I]; also zeroes cnt[]
  k_transpose_all<<<dim3(704, 1, 24), 256, 0, stream>>>(Wg, Wu, Wd, WgT, WuT,
                                                        WdT, cnt);
  k_gating<<<TOKS / 4, 256, 0, stream>>>(x, gw, logits_out, cnt, tidx, tprb);
  k_build<<<TOKS, 256, 0, stream>>>(x, tidx, cnt, A);
  k_gemm1<<<dim3(IDIM / 64, MTILES), 256, 0, stream>>>(A, WgT, WuT, act, cnt);
  k_gemm2<<<dim3(HDIM / 128, MTILES), 256, 0, stream>>>(act, WdT, partial, cnt);
  k_combine<<<TOKS, 256, 0, stream>>>(partial, tidx, cnt, tprb, out);
}

// Round 3
// 591.239 us; speedup vs baseline: 1.0315x; 1.0315x over previous
//
#include <hip/hip_runtime.h>

// ---------------------------------------------------------------------------
// MoE top-2 of 8 experts, SwiGLU. B=2,S=2048 -> T=4096 tokens, H=1024, I=2816.
// fp64 gating (selection fidelity), bf16 MFMA grouped GEMMs on top-2 rows.
// R6: revert GEMMs to R4 shapes (R5 fat tiles cut residency: acc AGPRs count
// against the unified 512-reg budget -> 236 total regs -> 2 blocks/CU,
// Occ 30->19.5%, Mfma 35->29.7). R4 = 136 total regs = 3 blocks/CU.
// Experiment: __launch_bounds__(256,4) on gemm1 only (compiler must fit 128
// total regs -> 4 blocks/CU). gemm2 byte-identical to R4 for attribution.
// Keep R5 aux wins: no k_prefix (cnt-derived tile_map/offsets), fused
// transpose, rank-in-gating, atomic-free build/combine.
// ---------------------------------------------------------------------------

namespace {
constexpr int TOKS = 4096;
constexpr int HDIM = 1024;
constexpr int IDIM = 2816;
constexpr int NEXP = 8;
constexpr int NROW = 8192;  // TOKS * 2 assignments
constexpr int MTILES = 72;  // >= worst-case sum of ceil(cnt_e/128)

// workspace layout (bytes)
constexpr size_t WGT_OFF = 0;                         // bf16 Wg^T  [E][I][H]
constexpr size_t WUT_OFF = 46137344;                  // bf16 Wu^T  [E][I][H]
constexpr size_t WDT_OFF = 92274688;                  // bf16 Wd^T  [E][H][I]
constexpr size_t A_OFF   = 138412032;                 // bf16 A     [8192][H]
constexpr size_t ACT_OFF = 155189248;                 // bf16 act   [8192][I]
constexpr size_t CNT_OFF = 201326592;                 // int[8]
constexpr size_t TIX_OFF = CNT_OFF + 1024;            // int4[4096] (e0,e1,r0,r1)
constexpr size_t TPR_OFF = CNT_OFF + 66560;           // float2[4096]
// partial fp32 [8192][H] aliases Wg^T region (GEMM1 done before GEMM2 writes)
constexpr size_t PRT_OFF = 0;                         // 33554432 <= 46137344
}  // namespace

typedef __attribute__((ext_vector_type(8))) short short8;
typedef __attribute__((ext_vector_type(8))) unsigned short ushort8;
typedef __attribute__((ext_vector_type(4))) float f32x4;

__device__ __forceinline__ unsigned short f2bf(float f) {
  union { float f; unsigned int u; } v; v.f = f;
  unsigned int u = v.u;
  return (unsigned short)((u + 0x7fffu + ((u >> 16) & 1u)) >> 16);  // RNE
}

__device__ __forceinline__ void gl2lds16(const void* g, void* l) {
  __builtin_amdgcn_global_load_lds(
      (const __attribute__((address_space(1))) void*)g,
      (__attribute__((address_space(3))) void*)l, 16, 0, 0);
}

// Derive (e, m0, off, ne) for 128-row m-tile index y from cnt[8]. e<0: no tile.
__device__ __forceinline__ void tile_map(const int* __restrict__ cnt, int y,
                                         int& e, int& m0, int& off, int& ne) {
  e = -1; m0 = 0; off = 0; ne = 0;
  int s = 0;
#pragma unroll
  for (int ee = 0; ee < NEXP; ++ee) {
    int c = cnt[ee];
    int nt = (c + 127) >> 7;
    if (e < 0) {
      if (y < nt) { e = ee; m0 = y << 7; off = s; ne = c; }
      else y -= nt;
    }
    s += c;
  }
}

// ------------- fused fp32 [R][C] -> bf16 [C][R] transpose (all 3 W) --------
// z: 0..7 = Wg expert e, 8..15 = Wu, 16..23 = Wd. 64x64 tiles, float4 reads,
// ushort8 stores. Block (0,0,0) also zeroes cnt[] (replaces k_init).
__global__ __launch_bounds__(256) void k_transpose_all(
    const float* __restrict__ Wg, const float* __restrict__ Wu,
    const float* __restrict__ Wd, unsigned short* __restrict__ WgT,
    unsigned short* __restrict__ WuT, unsigned short* __restrict__ WdT,
    int* __restrict__ cnt) {
  const int z = blockIdx.z;
  if (z == 0 && blockIdx.x == 0 && threadIdx.x < NEXP) cnt[threadIdx.x] = 0;
  const float* in; unsigned short* out; int C, R;
  if (z < 8)       { in = Wg; out = WgT; C = IDIM; R = HDIM; }
  else if (z < 16) { in = Wu; out = WuT; C = IDIM; R = HDIM; }
  else             { in = Wd; out = WdT; C = HDIM; R = IDIM; }
  const size_t eoff = (size_t)(z & 7) * HDIM * IDIM;
  in += eoff; out += eoff;
  const int nbx = C / 64;
  const int c0 = (blockIdx.x % nbx) * 64, r0 = (blockIdx.x / nbx) * 64;
  __shared__ float tile[64][65];
  const int tid = threadIdx.x;
  const int rr = tid >> 4, cc4 = (tid & 15) * 4;
#pragma unroll
  for (int i = 0; i < 4; ++i) {
    int r = rr + i * 16;
    float4 v = *(const float4*)(in + (size_t)(r0 + r) * C + c0 + cc4);
    tile[r][cc4 + 0] = v.x; tile[r][cc4 + 1] = v.y;
    tile[r][cc4 + 2] = v.z; tile[r][cc4 + 3] = v.w;
  }
  __syncthreads();
  const int j = tid & 7;  // 16B chunk within out row
#pragma unroll
  for (int i = 0; i < 2; ++i) {
    int c = (tid >> 3) + i * 32;
    ushort8 o;
#pragma unroll
    for (int k = 0; k < 8; ++k) o[k] = f2bf(tile[j * 8 + k][c]);
    *(ushort8*)(out + (size_t)(c0 + c) * R + r0 + j * 8) = o;
  }
}

// ------------------------------- gating ------------------------------------
__global__ __launch_bounds__(256) void k_gating(
    const float* __restrict__ x, const float* __restrict__ gw,
    float* __restrict__ logits_out, int* __restrict__ cnt,
    int4* __restrict__ tidx, float2* __restrict__ tprb) {
  const int lane = threadIdx.x & 63;
  const int t = blockIdx.x * 4 + (threadIdx.x >> 6);
  const float4* xr = (const float4*)(x + (size_t)t * HDIM);
  double acc[8];
#pragma unroll
  for (int e = 0; e < 8; ++e) acc[e] = 0.0;
#pragma unroll
  for (int jj = 0; jj < 4; ++jj) {
    float4 xv = xr[lane + jj * 64];
    const int hb = (lane + jj * 64) * 4;
    const float xs[4] = {xv.x, xv.y, xv.z, xv.w};
#pragma unroll
    for (int c = 0; c < 4; ++c) {
      const float4* g = (const float4*)(gw + (size_t)(hb + c) * 8);
      float4 g0 = g[0], g1 = g[1];
      acc[0] += (double)xs[c] * g0.x; acc[1] += (double)xs[c] * g0.y;
      acc[2] += (double)xs[c] * g0.z; acc[3] += (double)xs[c] * g0.w;
      acc[4] += (double)xs[c] * g1.x; acc[5] += (double)xs[c] * g1.y;
      acc[6] += (double)xs[c] * g1.z; acc[7] += (double)xs[c] * g1.w;
    }
  }
#pragma unroll
  for (int off = 32; off > 0; off >>= 1) {
#pragma unroll
    for (int e = 0; e < 8; ++e) acc[e] += __shfl_down(acc[e], off);
  }
  if (lane == 0) {
    float lg[8];
#pragma unroll
    for (int e = 0; e < 8; ++e) lg[e] = (float)acc[e];
#pragma unroll
    for (int e = 0; e < 8; ++e) logits_out[(size_t)t * 8 + e] = lg[e];
    float v0 = lg[0]; int i0 = 0; float v1 = -3.0e38f; int i1 = 0;
#pragma unroll
    for (int e = 1; e < 8; ++e) {
      if (lg[e] > v0) { v1 = v0; i1 = i0; v0 = lg[e]; i0 = e; }
      else if (lg[e] > v1) { v1 = lg[e]; i1 = e; }
    }
    float ex = expf(v1 - v0);
    float p0 = 1.0f / (1.0f + ex);
    float p1 = ex / (1.0f + ex);
    int r0 = atomicAdd(&cnt[i0], 1);   // within-expert rank
    int r1 = atomicAdd(&cnt[i1], 1);
    tidx[t] = make_int4(i0, i1, r0, r1);
    tprb[t] = make_float2(p0, p1);
  }
}

// --------------- gather x rows to compact bf16 A (no atomics) --------------
__global__ __launch_bounds__(256) void k_build(
    const float* __restrict__ x, const int4* __restrict__ tidx,
    const int* __restrict__ cnt, unsigned short* __restrict__ A) {
  const int t = blockIdx.x;
  const int4 ii = tidx[t];
  int o0 = 0, o1 = 0;
#pragma unroll
  for (int e = 0; e < NEXP - 1; ++e) {
    int c = cnt[e];
    o0 += (e < ii.x) ? c : 0;
    o1 += (e < ii.y) ? c : 0;
  }
  const int r0 = o0 + ii.z, r1 = o1 + ii.w;
  float4 v = ((const float4*)(x + (size_t)t * HDIM))[threadIdx.x];
  ushort4 b;
  b.x = f2bf(v.x); b.y = f2bf(v.y); b.z = f2bf(v.z); b.w = f2bf(v.w);
  ((ushort4*)(A + (size_t)r0 * HDIM))[threadIdx.x] = b;
  ((ushort4*)(A + (size_t)r1 * HDIM))[threadIdx.x] = b;
}

// ---------------- GEMM1: act = silu(A*Wg^T) * (A*Wu^T)  (bf16) -------------
// 128(M) x 64(N) tile, dual B, BK=64, 16x16x32 MFMA, XOR-swizzled LDS.
// __launch_bounds__(256,4): force total regs <= 128 (incl 64 acc AGPRs,
// unified file) -> 4 blocks/CU residency (R4 was 136 regs -> 3 blocks).
__global__ __launch_bounds__(256, 4) void k_gemm1(
    const unsigned short* __restrict__ A, const unsigned short* __restrict__ WgT,
    const unsigned short* __restrict__ WuT, unsigned short* __restrict__ act,
    const int* __restrict__ cnt) {
  int e, m0, off, ne;
  tile_map(cnt, blockIdx.y, e, m0, off, ne);
  if (e < 0) return;
  const int n0 = blockIdx.x * 64;
  const unsigned short* Bg = WgT + ((size_t)e * IDIM + n0) * HDIM;
  const unsigned short* Bu = WuT + ((size_t)e * IDIM + n0) * HDIM;

  __shared__ unsigned short As[128 * 64];   // 16 KB
  __shared__ unsigned short Bgs[64 * 64];   // 8 KB
  __shared__ unsigned short Bus[64 * 64];   // 8 KB

  const int tid = threadIdx.x, w = tid >> 6, lane = tid & 63;
  const int lrow8 = lane >> 3;                       // 0..7 row in 1KB chunk
  const int swz = ((lane & 7) ^ lrow8) * 8;          // swizzled src column
  const int m16 = lane & 15, quad = lane >> 4, l7 = lane & 7;

  f32x4 accg[2][4], accu[2][4];
#pragma unroll
  for (int mi = 0; mi < 2; ++mi)
#pragma unroll
    for (int ni = 0; ni < 4; ++ni) {
      accg[mi][ni] = (f32x4){0.f, 0.f, 0.f, 0.f};
      accu[mi][ni] = (f32x4){0.f, 0.f, 0.f, 0.f};
    }

  for (int kt = 0; kt < HDIM / 64; ++kt) {
    const int k0 = kt * 64;
#pragma unroll
    for (int i = 0; i < 4; ++i) {
      int gr = off + m0 + w * 32 + i * 8 + lrow8;
      gr = gr > (NROW - 1) ? (NROW - 1) : gr;
      gl2lds16(A + (size_t)gr * HDIM + k0 + swz, &As[(w * 32 + i * 8) * 64]);
    }
#pragma unroll
    for (int i = 0; i < 2; ++i) {
      int rl = w * 16 + i * 8 + lrow8;
      gl2lds16(Bg + (size_t)rl * HDIM + k0 + swz, &Bgs[(w * 16 + i * 8) * 64]);
      gl2lds16(Bu + (size_t)rl * HDIM + k0 + swz, &Bus[(w * 16 + i * 8) * 64]);
    }
    __syncthreads();
#pragma unroll
    for (int kk = 0; kk < 2; ++kk) {
      const int jc = ((kk * 4 + quad) ^ l7) * 8;     // swizzled read column
      short8 af[2], bgf[4], buf[4];
#pragma unroll
      for (int mi = 0; mi < 2; ++mi)
        af[mi] = *(const short8*)&As[(w * 32 + mi * 16 + m16) * 64 + jc];
#pragma unroll
      for (int ni = 0; ni < 4; ++ni) {
        bgf[ni] = *(const short8*)&Bgs[(ni * 16 + m16) * 64 + jc];
        buf[ni] = *(const short8*)&Bus[(ni * 16 + m16) * 64 + jc];
      }
#pragma unroll
      for (int mi = 0; mi < 2; ++mi)
#pragma unroll
        for (int ni = 0; ni < 4; ++ni) {
          accg[mi][ni] = __builtin_amdgcn_mfma_f32_16x16x32_bf16(
              af[mi], bgf[ni], accg[mi][ni], 0, 0, 0);
          accu[mi][ni] = __builtin_amdgcn_mfma_f32_16x16x32_bf16(
              af[mi], buf[ni], accu[mi][ni], 0, 0, 0);
        }
    }
    __syncthreads();
  }
  // epilogue: silu(g)*u -> bf16, staged through As for 16B stores
#pragma unroll
  for (int mi = 0; mi < 2; ++mi)
#pragma unroll
    for (int ni = 0; ni < 4; ++ni)
#pragma unroll
      for (int r = 0; r < 4; ++r) {
        int ml = w * 32 + mi * 16 + quad * 4 + r;
        float g = accg[mi][ni][r];
        float u = accu[mi][ni][r];
        float s = g / (1.0f + __expf(-g));
        As[ml * 64 + ni * 16 + m16] = f2bf(s * u);
      }
  __syncthreads();
#pragma unroll
  for (int i = 0; i < 4; ++i) {
    int chunk = i * 256 + tid;
    int row = chunk >> 3, j = chunk & 7;
    if (m0 + row < ne)
      *(ushort8*)&act[(size_t)(off + m0 + row) * IDIM + n0 + j * 8] =
          *(const ushort8*)&As[row * 64 + j * 8];
  }
}

// ---------------- GEMM2: partial = act * Wd^T  (bf16 -> fp32) --------------
// 128x128 tile, 4 waves 2x2, BK=64, XOR-swizzled LDS (R4-identical).
__global__ __launch_bounds__(256, 2) void k_gemm2(
    const unsigned short* __restrict__ act, const unsigned short* __restrict__ WdT,
    float* __restrict__ partial, const int* __restrict__ cnt) {
  int e, m0, off, ne;
  tile_map(cnt, blockIdx.y, e, m0, off, ne);
  if (e < 0) return;
  const int n0 = blockIdx.x * 128;
  const unsigned short* B = WdT + ((size_t)e * HDIM + n0) * IDIM;

  __shared__ unsigned short As[128 * 64];
  __shared__ unsigned short Bs[128 * 64];

  const int tid = threadIdx.x, w = tid >> 6, lane = tid & 63;
  const int lrow8 = lane >> 3;
  const int swz = ((lane & 7) ^ lrow8) * 8;
  const int m16 = lane & 15, quad = lane >> 4, l7 = lane & 7;
  const int wm = (w >> 1) * 64, wn = (w & 1) * 64;

  f32x4 acc[4][4];
#pragma unroll
  for (int mi = 0; mi < 4; ++mi)
#pragma unroll
    for (int ni = 0; ni < 4; ++ni) acc[mi][ni] = (f32x4){0.f, 0.f, 0.f, 0.f};

  for (int kt = 0; kt < IDIM / 64; ++kt) {
    const int k0 = kt * 64;
#pragma unroll
    for (int i = 0; i < 4; ++i) {
      int rl = w * 32 + i * 8 + lrow8;
      int gr = off + m0 + rl;
      gr = gr > (NROW - 1) ? (NROW - 1) : gr;
      gl2lds16(act + (size_t)gr * IDIM + k0 + swz, &As[(w * 32 + i * 8) * 64]);
      gl2lds16(B + (size_t)rl * IDIM + k0 + swz, &Bs[(w * 32 + i * 8) * 64]);
    }
    __syncthreads();
#pragma unroll
    for (int kk = 0; kk < 2; ++kk) {
      const int jc = ((kk * 4 + quad) ^ l7) * 8;
      short8 af[4], bf[4];
#pragma unroll
      for (int mi = 0; mi < 4; ++mi)
        af[mi] = *(const short8*)&As[(wm + mi * 16 + m16) * 64 + jc];
#pragma unroll
      for (int ni = 0; ni < 4; ++ni)
        bf[ni] = *(const short8*)&Bs[(wn + ni * 16 + m16) * 64 + jc];
#pragma unroll
      for (int mi = 0; mi < 4; ++mi)
#pragma unroll
        for (int ni = 0; ni < 4; ++ni)
          acc[mi][ni] = __builtin_amdgcn_mfma_f32_16x16x32_bf16(
              af[mi], bf[ni], acc[mi][ni], 0, 0, 0);
    }
    __syncthreads();
  }
#pragma unroll
  for (int mi = 0; mi < 4; ++mi)
#pragma unroll
    for (int ni = 0; ni < 4; ++ni)
#pragma unroll
      for (int r = 0; r < 4; ++r) {
        int ml = wm + mi * 16 + quad * 4 + r;
        if (m0 + ml < ne)
          partial[(size_t)(off + m0 + ml) * HDIM + n0 + wn + ni * 16 + m16] =
              acc[mi][ni][r];
      }
}

// ------------------- combine: out = p0*row0 + p1*row1 ----------------------
__global__ __launch_bounds__(256) void k_combine(
    const float* __restrict__ partial, const int4* __restrict__ tidx,
    const int* __restrict__ cnt, const float2* __restrict__ tprb,
    float* __restrict__ out) {
  const int t = blockIdx.x;
  const int4 ii = tidx[t];
  int o0 = 0, o1 = 0;
#pragma unroll
  for (int e = 0; e < NEXP - 1; ++e) {
    int c = cnt[e];
    o0 += (e < ii.x) ? c : 0;
    o1 += (e < ii.y) ? c : 0;
  }
  const int r0 = o0 + ii.z, r1 = o1 + ii.w;
  const float2 p = tprb[t];
  float4 a = ((const float4*)(partial + (size_t)r0 * HDIM))[threadIdx.x];
  float4 b = ((const float4*)(partial + (size_t)r1 * HDIM))[threadIdx.x];
  float4 o;
  o.x = p.x * a.x + p.y * b.x;
  o.y = p.x * a.y + p.y * b.y;
  o.z = p.x * a.z + p.y * b.z;
  o.w = p.x * a.w + p.y * b.w;
  ((float4*)(out + (size_t)t * HDIM))[threadIdx.x] = o;
}

// ---------------------------------------------------------------------------
extern "C" void kernel_launch(void* const* d_in, const int* in_sizes, int n_in,
                              void* d_out, int out_size, void* d_ws, size_t ws_size,
                              hipStream_t stream) {
  const float* x  = (const float*)d_in[0];
  const float* gw = (const float*)d_in[1];
  const float* Wg = (const float*)d_in[2];
  const float* Wu = (const float*)d_in[3];
  const float* Wd = (const float*)d_in[4];
  float* out = (float*)d_out;
  char* ws = (char*)d_ws;

  unsigned short* WgT = (unsigned short*)(ws + WGT_OFF);
  unsigned short* WuT = (unsigned short*)(ws + WUT_OFF);
  unsigned short* WdT = (unsigned short*)(ws + WDT_OFF);
  unsigned short* A   = (unsigned short*)(ws + A_OFF);
  unsigned short* act = (unsigned short*)(ws + ACT_OFF);
  float* partial = (float*)(ws + PRT_OFF);
  int* cnt  = (int*)(ws + CNT_OFF);
  int4* tidx = (int4*)(ws + TIX_OFF);
  float2* tprb = (float2*)(ws + TPR_OFF);

  float* logits_out = out + (size_t)TOKS * HDIM;  // output 1 region

  // Wg,Wu: [H][I] -> [I][H]; Wd: [I][H] -> [H][I]; also zeroes cnt[]
  k_transpose_all<<<dim3(704, 1, 24), 256, 0, stream>>>(Wg, Wu, Wd, WgT, WuT,
                                                        WdT, cnt);
  k_gating<<<TOKS / 4, 256, 0, stream>>>(x, gw, logits_out, cnt, tidx, tprb);
  k_build<<<TOKS, 256, 0, stream>>>(x, tidx, cnt, A);
  k_gemm1<<<dim3(IDIM / 64, MTILES), 256, 0, stream>>>(A, WgT, WuT, act, cnt);
  k_gemm2<<<dim3(HDIM / 128, MTILES), 256, 0, stream>>>(act, WdT, partial, cnt);
  k_combine<<<TOKS, 256, 0, stream>>>(partial, tidx, cnt, tprb, out);
}